// Round 22
// baseline (63.536 us; speedup 1.0000x reference)
//
#include <hip/hip_runtime.h>
#include <stdint.h>

#define ALPHA 0.2f
#define LOG2E 1.44269504089f
#define SKIP_THR 24.0f

typedef __attribute__((ext_vector_type(8))) short s16x8;
typedef __attribute__((ext_vector_type(4))) float f32x4;
typedef __attribute__((ext_vector_type(4))) unsigned u32x4;

__device__ __forceinline__ unsigned short f2bf(float f) {
    union { float f; unsigned u; } c; c.f = f;
    unsigned u = c.u;
    u += 0x7fffu + ((u >> 16) & 1u);
    return (unsigned short)(u >> 16);
}

// ---- prep: wT bf16 [c=256][f=256] (c=(h,e)) + wa1/wa2 = log2e * W@a{1,2} ----
__global__ void k_prep_w(const float* __restrict__ weight, const float* __restrict__ att,
                         unsigned short* __restrict__ wT, float* __restrict__ wa1,
                         float* __restrict__ wa2) {
    int blk = blockIdx.x, t = threadIdx.x;
    if (blk < 256) {
        int c = blk, h = c >> 5, e = c & 31;
        wT[c * 256 + t] = f2bf(weight[h * 8192 + t * 32 + e]);
    } else {
        int id = blk - 256, h = id >> 1, which = id & 1;
        float s = 0.f;
        for (int e = 0; e < 32; ++e)
            s += weight[h * 8192 + t * 32 + e] * att[h * 64 + which * 32 + e];
        s *= LOG2E;   // scores in log2 domain (leaky commutes with positive scale)
        (which ? wa2 : wa1)[h * 256 + t] = s;
    }
}

// ---- fused (r15-proven): adj->gmask, x->LDS (fp32 + swizzled bf16),
//      s1/s2 dots (4-acc ILP), Wh^T MFMA ----
__global__ void __launch_bounds__(512) k_pre(const int* __restrict__ adj,
                                             unsigned* __restrict__ gmask,
                                             const float* __restrict__ x,
                                             const unsigned short* __restrict__ wT,
                                             const float* __restrict__ wa1,
                                             const float* __restrict__ wa2,
                                             float* __restrict__ s1,
                                             float* __restrict__ s2,
                                             unsigned short* __restrict__ WhT) {
    __shared__ unsigned char adjb[16][1024];   // 0/1 bytes, col ^ ((row&7)<<4) swizzle
    __shared__ float xs[16][260];
    __shared__ unsigned short x16s[16][256];   // bf16 rows, 16B-unit XOR swizzle
    int blk = blockIdx.x;                      // blk = b*64 + mt
    int t = threadIdx.x, w = t >> 6, l = t & 63;
    int b = blk >> 6;
    const int* abase = adj + blk * 16384;
#pragma unroll
    for (int it = 0; it < 8; ++it) {
        int f = it * 512 + t;
        int4 v = *(const int4*)(abase + f * 4);
        int row = f >> 8, col = (f & 255) * 4;
        unsigned p1 = __builtin_amdgcn_perm((unsigned)v.y, (unsigned)v.x, 0x00000400u);
        unsigned p2 = __builtin_amdgcn_perm((unsigned)v.w, (unsigned)v.z, 0x00000400u);
        unsigned pk = __builtin_amdgcn_perm(p2, p1, 0x05040100u);
        *(unsigned*)&adjb[row][col ^ ((row & 7) << 4)] = pk;
    }
    const float* xbase = x + blk * 4096;
#pragma unroll
    for (int it = 0; it < 2; ++it) {
        int f = it * 512 + t;
        float4 xv = *(const float4*)(xbase + f * 4);
        int row = f >> 6, col = (f & 63) * 4;
        *(float4*)&xs[row][col] = xv;
        ushort4 hv;
        hv.x = f2bf(xv.x); hv.y = f2bf(xv.y); hv.z = f2bf(xv.z); hv.w = f2bf(xv.w);
        *(ushort4*)((char*)&x16s[0][0] + ((row * 512 + col * 2) ^ ((row & 7) << 4))) = hv;
    }
    __syncthreads();
    if (w < 4) {
        for (int k = 0; k < 64; ++k) {
            int task = w * 64 + k;
            int row = task >> 4, ch = task & 15;
            unsigned char byv = adjb[row][(ch * 64 + l) ^ ((row & 7) << 4)];
            unsigned long long mk = __ballot(byv != 0);
            if (l == 0) {
                unsigned* dst = gmask + (blk * 16 + row) * 32 + ch * 2;
                dst[0] = (unsigned)mk;
                dst[1] = (unsigned)(mk >> 32);
            }
        }
    } else {
        int td = (w - 4) * 64 + l;
        int row = td & 15, grp = td >> 4;
        int h = grp >> 1, which = grp & 1;
        const float* wap = (which ? wa2 : wa1) + h * 256;
        float sa0 = 0.f, sa1 = 0.f, sa2 = 0.f, sa3 = 0.f;   // 4 indep chains
#pragma unroll
        for (int f = 0; f < 256; f += 16) {
            f32x4 x0 = *(const f32x4*)&xs[row][f];
            f32x4 w0 = *(const f32x4*)&wap[f];
            f32x4 x1 = *(const f32x4*)&xs[row][f + 4];
            f32x4 w1 = *(const f32x4*)&wap[f + 4];
            f32x4 x2 = *(const f32x4*)&xs[row][f + 8];
            f32x4 w2 = *(const f32x4*)&wap[f + 8];
            f32x4 x3 = *(const f32x4*)&xs[row][f + 12];
            f32x4 w3 = *(const f32x4*)&wap[f + 12];
            sa0 += x0[0]*w0[0] + x0[1]*w0[1] + x0[2]*w0[2] + x0[3]*w0[3];
            sa1 += x1[0]*w1[0] + x1[1]*w1[1] + x1[2]*w1[2] + x1[3]*w1[3];
            sa2 += x2[0]*w2[0] + x2[1]*w2[1] + x2[2]*w2[2] + x2[3]*w2[3];
            sa3 += x3[0]*w3[0] + x3[1]*w3[1] + x3[2]*w3[2] + x3[3]*w3[3];
        }
        float s = (sa0 + sa1) + (sa2 + sa3);
        int m = (blk & 63) * 16 + row;
        (which ? s2 : s1)[(b * 8 + h) * 1024 + m] = s;
    }
    int lrow = l & 15, lk = l >> 4;
#pragma unroll
    for (int ct = 0; ct < 2; ++ct) {
        int c0 = (w * 2 + ct) * 16;
        f32x4 acc = {0, 0, 0, 0};
        const unsigned short* ap = wT + (c0 + lrow) * 256 + lk * 8;
#pragma unroll
        for (int k0 = 0; k0 < 256; k0 += 32) {
            s16x8 af = *(const s16x8*)(ap + k0);
            s16x8 bf = *(const s16x8*)((char*)&x16s[0][0] +
                        ((lrow * 512 + (lk * 8 + k0) * 2) ^ ((lrow & 7) << 4)));
            acc = __builtin_amdgcn_mfma_f32_16x16x32_bf16(af, bf, acc, 0, 0, 0);
        }
#pragma unroll
        for (int j = 0; j < 4; ++j) {
            int c = c0 + lk * 4 + j;
            WhT[(b * 256 + c) * 1024 + (blk & 63) * 16 + lrow] = f2bf(acc[j]);
        }
    }
}

// ---- top-16 of s2 per (b,h): sorted desc values + indices (r16-proven) ----
__global__ void __launch_bounds__(64) k_top(const float* __restrict__ s2,
                                            float* __restrict__ tval,
                                            unsigned* __restrict__ tidx) {
    int bh = blockIdx.x, l = threadIdx.x;
    const float* p = s2 + bh * 1024;
    float v[16];
#pragma unroll
    for (int k = 0; k < 4; ++k) {
        f32x4 x4 = *(const f32x4*)(p + l * 16 + k * 4);
        v[k * 4 + 0] = x4[0]; v[k * 4 + 1] = x4[1];
        v[k * 4 + 2] = x4[2]; v[k * 4 + 3] = x4[3];
    }
    unsigned used = 0;
    for (int r = 0; r < 16; ++r) {
        float lmax = -3.0e38f; int larg = 0;
#pragma unroll
        for (int k = 0; k < 16; ++k) {
            float c = ((used >> k) & 1u) ? -3.0e38f : v[k];
            if (c > lmax) { lmax = c; larg = k; }
        }
        float wmax = lmax;
#pragma unroll
        for (int off = 32; off >= 1; off >>= 1) wmax = fmaxf(wmax, __shfl_xor(wmax, off));
        unsigned long long hm = __ballot(lmax == wmax);
        int fl = (int)__builtin_ctzll(hm);
        if (l == fl) {
            tval[bh * 16 + r] = wmax;
            tidx[bh * 16 + r] = (unsigned)(l * 16 + larg);
            used |= 1u << larg;
        }
    }
}

// ---- attention v22: 512 blocks x 512 thr, wave = head (8 heads/block);
//      full-row waves; top-16-probe mx; tile-skip; s2/WhT from L2 ----
__global__ void __launch_bounds__(512, 4) k_attn(const unsigned* __restrict__ gmask,
                                                 const float* __restrict__ s1,
                                                 const float* __restrict__ s2,
                                                 const float* __restrict__ tval,
                                                 const unsigned* __restrict__ tidx,
                                                 const unsigned short* __restrict__ WhT,
                                                 float* __restrict__ out) {
    __shared__ unsigned amaskw[16][36];
    __shared__ float s1s[8][16];
    __shared__ float ptmx[8][32][4];
    __shared__ float tmx[8][32];
    int bid = blockIdx.x;
    int o = (bid & 7) * 64 + (bid >> 3);   // XCD swizzle: each XCD owns one b
    int b = o >> 6, mt = o & 63, m0 = mt * 16;
    int t = threadIdx.x, w = t >> 6, l = t & 63;
    amaskw[t >> 5][t & 31] = gmask[(b * 1024 + m0) * 32 + t];
    if (t < 128) s1s[t >> 4][t & 15] = s1[b * 8192 + (t >> 4) * 1024 + m0 + (t & 15)];
    // per-tile unmasked s2 maxes (from global; L2-warm): 1024 tasks / 512 thr
#pragma unroll
    for (int it = 0; it < 2; ++it) {
        int task = it * 512 + t;
        int hd2 = task >> 7, rem = task & 127, tile = rem >> 2, part = rem & 3;
        const float* sp = s2 + b * 8192 + hd2 * 1024 + tile * 32 + part * 8;
        f32x4 a = *(const f32x4*)sp;
        f32x4 c = *(const f32x4*)(sp + 4);
        ptmx[hd2][tile][part] = fmaxf(fmaxf(fmaxf(a[0], a[1]), fmaxf(a[2], a[3])),
                                      fmaxf(fmaxf(c[0], c[1]), fmaxf(c[2], c[3])));
    }
    __syncthreads();
    if (t < 256) {
        int hd2 = t >> 5, tile = t & 31;
        tmx[hd2][tile] = fmaxf(fmaxf(ptmx[hd2][tile][0], ptmx[hd2][tile][1]),
                               fmaxf(ptmx[hd2][tile][2], ptmx[hd2][tile][3]));
    }
    __syncthreads();
    int m = l & 15, q = l >> 4;
    int h = w;
    // tmx for this head into registers (broadcast LDS reads)
    f32x4 tm[8];
#pragma unroll
    for (int k = 0; k < 8; ++k) tm[k] = *(const f32x4*)&tmx[w][k * 4];
    // ---- pass A': probe top-16 sorted ranks (exact w.h.p.; miss -> tv[15]
    //      upper bound; safe with select-before-exp) ----
    const float*    tv = tval + (b * 8 + h) * 16;
    const unsigned* ti = tidx + (b * 8 + h) * 16;
    f32x4 tvv[4]; u32x4 tiv[4];
#pragma unroll
    for (int k = 0; k < 4; ++k) {
        tvv[k] = *(const f32x4*)(tv + k * 4);
        tiv[k] = *(const u32x4*)(ti + k * 4);
    }
    float mxs2 = tvv[3][3];
#pragma unroll
    for (int j = 0; j < 16; ++j) {
        unsigned id = tiv[j >> 2][j & 3];
        unsigned wd = amaskw[m][id >> 5];
        unsigned bit = (wd >> (id & 31u)) & 1u;
        mxs2 = fmaxf(mxs2, bit ? tvv[j >> 2][j & 3] : -3.0e38f);
    }
    float s1v = s1s[w][m];
    float mxr = s1v + mxs2;
    float mx = fmaxf(mxr, ALPHA * mxr);   // >= leaky(any masked score): safe shift
    float cc1 = s1v - mx;
    float cc2 = fmaf(ALPHA, s1v, -mx);
    // ---- pass B: full row, tile-skip; s2/WhT straight from global ----
    f32x4 acc0 = {0,0,0,0}, acc1 = {0,0,0,0}, accs = {0,0,0,0};
    s16x8 ones;
#pragma unroll
    for (int u = 0; u < 8; ++u) ones[u] = (short)0x3F80;   // bf16 1.0
    const float* sgb = s2 + (b * 8 + h) * 1024 + q * 8;
    const unsigned short* bp0 = WhT + (b * 8 + h) * 32768 + m * 1024 + q * 8;
    const unsigned short* bp1 = bp0 + 16 * 1024;
#pragma unroll
    for (int i = 0; i < 32; ++i) {
        float tmf = tm[i >> 2][i & 3];
        float ub = fmaxf(tmf + cc1, fmaf(ALPHA, tmf, cc2));  // row's max arg in tile
        if (__any(ub >= -SKIP_THR)) {
            int n0 = i * 32;
            unsigned wm8 = amaskw[m][i] >> (q * 8);
            f32x4 svA = *(const f32x4*)(sgb + n0);
            f32x4 svB = *(const f32x4*)(sgb + n0 + 4);
            float pv[8];
#pragma unroll
            for (int u = 0; u < 8; ++u) {
                float sv = (u < 4 ? svA[u] : svB[u - 4]);
                float arg = fmaxf(sv + cc1, fmaf(ALPHA, sv, cc2));   // leaky-mx
                arg = ((wm8 >> u) & 1u) ? arg : -3.0e38f;            // select pre-exp
                pv[u] = __builtin_amdgcn_exp2f(arg);
            }
            u32x4 aw;
#pragma unroll
            for (int p = 0; p < 4; ++p) {
                union { float f; unsigned u; } lo, hi;
                lo.f = pv[2 * p]; hi.f = pv[2 * p + 1];
                aw[p] = __builtin_amdgcn_perm(hi.u, lo.u, 0x07060302u);  // 2xbf16 pack
            }
            s16x8 af = __builtin_bit_cast(s16x8, aw);
            s16x8 bf0 = *(const s16x8*)(bp0 + n0);
            s16x8 bf1 = *(const s16x8*)(bp1 + n0);
            acc0 = __builtin_amdgcn_mfma_f32_16x16x32_bf16(af, bf0, acc0, 0, 0, 0);
            acc1 = __builtin_amdgcn_mfma_f32_16x16x32_bf16(af, bf1, acc1, 0, 0, 0);
            accs = __builtin_amdgcn_mfma_f32_16x16x32_bf16(af, ones, accs, 0, 0, 0);
        }
    }
    // ---- epilogue: accs IS the row-sum (full row per wave) ----
#pragma unroll
    for (int j = 0; j < 4; ++j) {
        float inv = 1.f / accs[j];
        float v0 = acc0[j] * inv;
        float v1 = acc1[j] * inv;
        v0 = v0 > 0.f ? v0 : __expf(v0) - 1.f;
        v1 = v1 > 0.f ? v1 : __expf(v1) - 1.f;
        int mrow = q * 4 + j;
        float* op = &out[(b * 1024 + m0 + mrow) * 256 + h * 32];
        op[m] = v0;
        op[16 + m] = v1;
    }
}

extern "C" void kernel_launch(void* const* d_in, const int* in_sizes, int n_in,
                              void* d_out, int out_size, void* d_ws, size_t ws_size,
                              hipStream_t stream) {
    const float* x      = (const float*)d_in[0];
    const int*   adj    = (const int*)d_in[1];
    const float* weight = (const float*)d_in[2];
    const float* att    = (const float*)d_in[3];

    char* ws = (char*)d_ws;
    unsigned short* wT  = (unsigned short*)(ws);             // 128K
    unsigned short* WhT = (unsigned short*)(ws + 131072);    // 4M
    float* s1  = (float*)(ws + 4325376);                     // 256K
    float* s2  = (float*)(ws + 4587520);                     // 256K
    float* wa1 = (float*)(ws + 4849664);                     // 8K
    float* wa2 = (float*)(ws + 4857856);                     // 8K
    unsigned* gmask = (unsigned*)(ws + 4866048);             // 1M
    float*    tval  = (float*)(ws + 5914624);                // 4K
    unsigned* tidx  = (unsigned*)(ws + 5918720);             // 4K
    float* out = (float*)d_out;

    k_prep_w<<<272, 256, 0, stream>>>(weight, att, wT, wa1, wa2);
    k_pre<<<512, 512, 0, stream>>>(adj, gmask, x, wT, wa1, wa2, s1, s2, WhT);
    k_top<<<64, 64, 0, stream>>>(s2, tval, tidx);
    k_attn<<<512, 512, 0, stream>>>(gmask, s1, s2, tval, tidx, WhT, out);
}

// Round 24
// 62.971 us; speedup vs baseline: 1.0090x; 1.0090x over previous
//
#include <hip/hip_runtime.h>
#include <stdint.h>

#define ALPHA 0.2f
#define LOG2E 1.44269504089f
#define SKIP_THR 24.0f

typedef __attribute__((ext_vector_type(8))) short s16x8;
typedef __attribute__((ext_vector_type(4))) float f32x4;
typedef __attribute__((ext_vector_type(4))) unsigned u32x4;

__device__ __forceinline__ unsigned short f2bf(float f) {
    union { float f; unsigned u; } c; c.f = f;
    unsigned u = c.u;
    u += 0x7fffu + ((u >> 16) & 1u);
    return (unsigned short)(u >> 16);
}

// ---- prep: wT bf16 [c=256][f=256] (c=(h,e)) + wa1/wa2 = log2e * W@a{1,2} ----
__global__ void k_prep_w(const float* __restrict__ weight, const float* __restrict__ att,
                         unsigned short* __restrict__ wT, float* __restrict__ wa1,
                         float* __restrict__ wa2) {
    int blk = blockIdx.x, t = threadIdx.x;
    if (blk < 256) {
        int c = blk, h = c >> 5, e = c & 31;
        wT[c * 256 + t] = f2bf(weight[h * 8192 + t * 32 + e]);
    } else {
        int id = blk - 256, h = id >> 1, which = id & 1;
        float s = 0.f;
        for (int e = 0; e < 32; ++e)
            s += weight[h * 8192 + t * 32 + e] * att[h * 64 + which * 32 + e];
        s *= LOG2E;   // scores in log2 domain (leaky commutes with positive scale)
        (which ? wa2 : wa1)[h * 256 + t] = s;
    }
}

// ---- fused (r15/r22-proven): adj->gmask, x->LDS, s1/s2 dots (4-acc), Wh^T ----
__global__ void __launch_bounds__(512) k_pre(const int* __restrict__ adj,
                                             unsigned* __restrict__ gmask,
                                             const float* __restrict__ x,
                                             const unsigned short* __restrict__ wT,
                                             const float* __restrict__ wa1,
                                             const float* __restrict__ wa2,
                                             float* __restrict__ s1,
                                             float* __restrict__ s2,
                                             unsigned short* __restrict__ WhT) {
    __shared__ unsigned char adjb[16][1024];   // 0/1 bytes, col ^ ((row&7)<<4) swizzle
    __shared__ float xs[16][260];
    __shared__ unsigned short x16s[16][256];   // bf16 rows, 16B-unit XOR swizzle
    int blk = blockIdx.x;                      // blk = b*64 + mt
    int t = threadIdx.x, w = t >> 6, l = t & 63;
    int b = blk >> 6;
    const int* abase = adj + blk * 16384;
#pragma unroll
    for (int it = 0; it < 8; ++it) {
        int f = it * 512 + t;
        int4 v = *(const int4*)(abase + f * 4);
        int row = f >> 8, col = (f & 255) * 4;
        unsigned p1 = __builtin_amdgcn_perm((unsigned)v.y, (unsigned)v.x, 0x00000400u);
        unsigned p2 = __builtin_amdgcn_perm((unsigned)v.w, (unsigned)v.z, 0x00000400u);
        unsigned pk = __builtin_amdgcn_perm(p2, p1, 0x05040100u);
        *(unsigned*)&adjb[row][col ^ ((row & 7) << 4)] = pk;
    }
    const float* xbase = x + blk * 4096;
#pragma unroll
    for (int it = 0; it < 2; ++it) {
        int f = it * 512 + t;
        float4 xv = *(const float4*)(xbase + f * 4);
        int row = f >> 6, col = (f & 63) * 4;
        *(float4*)&xs[row][col] = xv;
        ushort4 hv;
        hv.x = f2bf(xv.x); hv.y = f2bf(xv.y); hv.z = f2bf(xv.z); hv.w = f2bf(xv.w);
        *(ushort4*)((char*)&x16s[0][0] + ((row * 512 + col * 2) ^ ((row & 7) << 4))) = hv;
    }
    __syncthreads();
    if (w < 4) {
        for (int k = 0; k < 64; ++k) {
            int task = w * 64 + k;
            int row = task >> 4, ch = task & 15;
            unsigned char byv = adjb[row][(ch * 64 + l) ^ ((row & 7) << 4)];
            unsigned long long mk = __ballot(byv != 0);
            if (l == 0) {
                unsigned* dst = gmask + (blk * 16 + row) * 32 + ch * 2;
                dst[0] = (unsigned)mk;
                dst[1] = (unsigned)(mk >> 32);
            }
        }
    } else {
        int td = (w - 4) * 64 + l;
        int row = td & 15, grp = td >> 4;
        int h = grp >> 1, which = grp & 1;
        const float* wap = (which ? wa2 : wa1) + h * 256;
        float sa0 = 0.f, sa1 = 0.f, sa2 = 0.f, sa3 = 0.f;   // 4 indep chains
#pragma unroll
        for (int f = 0; f < 256; f += 16) {
            f32x4 x0 = *(const f32x4*)&xs[row][f];
            f32x4 w0 = *(const f32x4*)&wap[f];
            f32x4 x1 = *(const f32x4*)&xs[row][f + 4];
            f32x4 w1 = *(const f32x4*)&wap[f + 4];
            f32x4 x2 = *(const f32x4*)&xs[row][f + 8];
            f32x4 w2 = *(const f32x4*)&wap[f + 8];
            f32x4 x3 = *(const f32x4*)&xs[row][f + 12];
            f32x4 w3 = *(const f32x4*)&wap[f + 12];
            sa0 += x0[0]*w0[0] + x0[1]*w0[1] + x0[2]*w0[2] + x0[3]*w0[3];
            sa1 += x1[0]*w1[0] + x1[1]*w1[1] + x1[2]*w1[2] + x1[3]*w1[3];
            sa2 += x2[0]*w2[0] + x2[1]*w2[1] + x2[2]*w2[2] + x2[3]*w2[3];
            sa3 += x3[0]*w3[0] + x3[1]*w3[1] + x3[2]*w3[2] + x3[3]*w3[3];
        }
        float s = (sa0 + sa1) + (sa2 + sa3);
        int m = (blk & 63) * 16 + row;
        (which ? s2 : s1)[(b * 8 + h) * 1024 + m] = s;
    }
    int lrow = l & 15, lk = l >> 4;
#pragma unroll
    for (int ct = 0; ct < 2; ++ct) {
        int c0 = (w * 2 + ct) * 16;
        f32x4 acc = {0, 0, 0, 0};
        const unsigned short* ap = wT + (c0 + lrow) * 256 + lk * 8;
#pragma unroll
        for (int k0 = 0; k0 < 256; k0 += 32) {
            s16x8 af = *(const s16x8*)(ap + k0);
            s16x8 bf = *(const s16x8*)((char*)&x16s[0][0] +
                        ((lrow * 512 + (lk * 8 + k0) * 2) ^ ((lrow & 7) << 4)));
            acc = __builtin_amdgcn_mfma_f32_16x16x32_bf16(af, bf, acc, 0, 0, 0);
        }
#pragma unroll
        for (int j = 0; j < 4; ++j) {
            int c = c0 + lk * 4 + j;
            WhT[(b * 256 + c) * 1024 + (blk & 63) * 16 + lrow] = f2bf(acc[j]);
        }
    }
}

// ---- top-16 of s2 per (b,h) + per-tile maxes tmxg[bh][32] ----
__global__ void __launch_bounds__(64) k_top(const float* __restrict__ s2,
                                            float* __restrict__ tval,
                                            unsigned* __restrict__ tidx,
                                            float* __restrict__ tmxg) {
    int bh = blockIdx.x, l = threadIdx.x;
    const float* p = s2 + bh * 1024;
    float v[16];
#pragma unroll
    for (int k = 0; k < 4; ++k) {
        f32x4 x4 = *(const f32x4*)(p + l * 16 + k * 4);
        v[k * 4 + 0] = x4[0]; v[k * 4 + 1] = x4[1];
        v[k * 4 + 2] = x4[2]; v[k * 4 + 3] = x4[3];
    }
    // per-tile (32-col) maxes: lane pair (2i,2i+1) covers tile i
    float m16 = v[0];
#pragma unroll
    for (int k = 1; k < 16; ++k) m16 = fmaxf(m16, v[k]);
    float tpair = fmaxf(m16, __shfl_xor(m16, 1));
    if ((l & 1) == 0) tmxg[bh * 32 + (l >> 1)] = tpair;
    // top-16 iterative selection (r16-proven)
    unsigned used = 0;
    for (int r = 0; r < 16; ++r) {
        float lmax = -3.0e38f; int larg = 0;
#pragma unroll
        for (int k = 0; k < 16; ++k) {
            float c = ((used >> k) & 1u) ? -3.0e38f : v[k];
            if (c > lmax) { lmax = c; larg = k; }
        }
        float wmax = lmax;
#pragma unroll
        for (int off = 32; off >= 1; off >>= 1) wmax = fmaxf(wmax, __shfl_xor(wmax, off));
        unsigned long long hm = __ballot(lmax == wmax);
        int fl = (int)__builtin_ctzll(hm);
        if (l == fl) {
            tval[bh * 16 + r] = wmax;
            tidx[bh * 16 + r] = (unsigned)(l * 16 + larg);
            used |= 1u << larg;
        }
    }
}

// ---- attention v24: slim prologue (amaskw + tmx load, ONE barrier);
//      top-16-probe mx; tile-skip; full-row waves (8 heads/block) ----
__global__ void __launch_bounds__(512, 4) k_attn(const unsigned* __restrict__ gmask,
                                                 const float* __restrict__ s1,
                                                 const float* __restrict__ s2,
                                                 const float* __restrict__ tval,
                                                 const unsigned* __restrict__ tidx,
                                                 const float* __restrict__ tmxg,
                                                 const unsigned short* __restrict__ WhT,
                                                 float* __restrict__ out) {
    __shared__ unsigned amaskw[16][36];
    __shared__ float tmxs[8][32];
    int bid = blockIdx.x;
    int o = (bid & 7) * 64 + (bid >> 3);   // XCD swizzle: each XCD owns one b
    int b = o >> 6, mt = o & 63, m0 = mt * 16;
    int t = threadIdx.x, w = t >> 6, l = t & 63;
    amaskw[t >> 5][t & 31] = gmask[(b * 1024 + m0) * 32 + t];
    if (t < 256) tmxs[t >> 5][t & 31] = tmxg[(b * 8 + (t >> 5)) * 32 + (t & 31)];
    __syncthreads();
    int m = l & 15, q = l >> 4;
    int h = w;
    f32x4 tm[8];
#pragma unroll
    for (int k = 0; k < 8; ++k) tm[k] = *(const f32x4*)&tmxs[w][k * 4];
    // ---- pass A': probe top-16 sorted ranks (exact w.h.p.; miss -> tv[15]
    //      upper bound; safe with select-before-exp) ----
    const float*    tv = tval + (b * 8 + h) * 16;
    const unsigned* ti = tidx + (b * 8 + h) * 16;
    f32x4 tvv[4]; u32x4 tiv[4];
#pragma unroll
    for (int k = 0; k < 4; ++k) {
        tvv[k] = *(const f32x4*)(tv + k * 4);
        tiv[k] = *(const u32x4*)(ti + k * 4);
    }
    float mxs2 = tvv[3][3];
#pragma unroll
    for (int j = 0; j < 16; ++j) {
        unsigned id = tiv[j >> 2][j & 3];
        unsigned wd = amaskw[m][id >> 5];
        unsigned bit = (wd >> (id & 31u)) & 1u;
        mxs2 = fmaxf(mxs2, bit ? tvv[j >> 2][j & 3] : -3.0e38f);
    }
    float s1v = s1[(b * 8 + h) * 1024 + m0 + m];   // L2-warm broadcast
    float mxr = s1v + mxs2;
    float mx = fmaxf(mxr, ALPHA * mxr);   // >= leaky(any masked score): safe shift
    float cc1 = s1v - mx;
    float cc2 = fmaf(ALPHA, s1v, -mx);
    // ---- pass B: full row, tile-skip; s2/WhT straight from global ----
    f32x4 acc0 = {0,0,0,0}, acc1 = {0,0,0,0}, accs = {0,0,0,0};
    s16x8 ones;
#pragma unroll
    for (int u = 0; u < 8; ++u) ones[u] = (short)0x3F80;   // bf16 1.0
    const float* sgb = s2 + (b * 8 + h) * 1024 + q * 8;
    const unsigned short* bp0 = WhT + (b * 8 + h) * 32768 + m * 1024 + q * 8;
    const unsigned short* bp1 = bp0 + 16 * 1024;
#pragma unroll
    for (int i = 0; i < 32; ++i) {
        float tmf = tm[i >> 2][i & 3];
        float ub = fmaxf(tmf + cc1, fmaf(ALPHA, tmf, cc2));  // row's max arg in tile
        if (__any(ub >= -SKIP_THR)) {
            int n0 = i * 32;
            unsigned wm8 = amaskw[m][i] >> (q * 8);
            f32x4 svA = *(const f32x4*)(sgb + n0);
            f32x4 svB = *(const f32x4*)(sgb + n0 + 4);
            float pv[8];
#pragma unroll
            for (int u = 0; u < 8; ++u) {
                float sv = (u < 4 ? svA[u] : svB[u - 4]);
                float arg = fmaxf(sv + cc1, fmaf(ALPHA, sv, cc2));   // leaky-mx
                arg = ((wm8 >> u) & 1u) ? arg : -3.0e38f;            // select pre-exp
                pv[u] = __builtin_amdgcn_exp2f(arg);
            }
            u32x4 aw;
#pragma unroll
            for (int p = 0; p < 4; ++p) {
                union { float f; unsigned u; } lo, hi;
                lo.f = pv[2 * p]; hi.f = pv[2 * p + 1];
                aw[p] = __builtin_amdgcn_perm(hi.u, lo.u, 0x07060302u);  // 2xbf16 pack
            }
            s16x8 af = __builtin_bit_cast(s16x8, aw);
            s16x8 bf0 = *(const s16x8*)(bp0 + n0);
            s16x8 bf1 = *(const s16x8*)(bp1 + n0);
            acc0 = __builtin_amdgcn_mfma_f32_16x16x32_bf16(af, bf0, acc0, 0, 0, 0);
            acc1 = __builtin_amdgcn_mfma_f32_16x16x32_bf16(af, bf1, acc1, 0, 0, 0);
            accs = __builtin_amdgcn_mfma_f32_16x16x32_bf16(af, ones, accs, 0, 0, 0);
        }
    }
    // ---- epilogue: accs IS the row-sum (full row per wave) ----
#pragma unroll
    for (int j = 0; j < 4; ++j) {
        float inv = 1.f / accs[j];
        float v0 = acc0[j] * inv;
        float v1 = acc1[j] * inv;
        v0 = v0 > 0.f ? v0 : __expf(v0) - 1.f;
        v1 = v1 > 0.f ? v1 : __expf(v1) - 1.f;
        int mrow = q * 4 + j;
        float* op = &out[(b * 1024 + m0 + mrow) * 256 + h * 32];
        op[m] = v0;
        op[16 + m] = v1;
    }
}

extern "C" void kernel_launch(void* const* d_in, const int* in_sizes, int n_in,
                              void* d_out, int out_size, void* d_ws, size_t ws_size,
                              hipStream_t stream) {
    const float* x      = (const float*)d_in[0];
    const int*   adj    = (const int*)d_in[1];
    const float* weight = (const float*)d_in[2];
    const float* att    = (const float*)d_in[3];

    char* ws = (char*)d_ws;
    unsigned short* wT  = (unsigned short*)(ws);             // 128K
    unsigned short* WhT = (unsigned short*)(ws + 131072);    // 4M
    float* s1  = (float*)(ws + 4325376);                     // 256K
    float* s2  = (float*)(ws + 4587520);                     // 256K
    float* wa1 = (float*)(ws + 4849664);                     // 8K
    float* wa2 = (float*)(ws + 4857856);                     // 8K
    unsigned* gmask = (unsigned*)(ws + 4866048);             // 1M
    float*    tval  = (float*)(ws + 5914624);                // 4K
    unsigned* tidx  = (unsigned*)(ws + 5918720);             // 4K
    float*    tmxg  = (float*)(ws + 5922816);                // 8K (end ~5.93MB)
    float* out = (float*)d_out;

    k_prep_w<<<272, 256, 0, stream>>>(weight, att, wT, wa1, wa2);
    k_pre<<<512, 512, 0, stream>>>(adj, gmask, x, wT, wa1, wa2, s1, s2, WhT);
    k_top<<<64, 64, 0, stream>>>(s2, tval, tidx, tmxg);
    k_attn<<<512, 512, 0, stream>>>(gmask, s1, s2, tval, tidx, tmxg, WhT, out);
}